// Round 1
// baseline (43.205 us; speedup 1.0000x reference)
//
#include <hip/hip_runtime.h>
#include <math.h>

#define HH 128
#define WW 128
#define TT 8
#define NG 1024

// Output (1,3,H,W,T) f32. Pixel order in the reference blend: p = (t*H + y)*W + x.
// Each block: 256 threads = 2 rows (r = t*128+y) of 128 x-values.
// Per block: cooperative per-gaussian setup -> LDS {A, fc0, fc1, fc2, B0, C0, B1, C1},
// then each thread Horner-evaluates sigma_hat(x) = A x^2 + B x + C (pre-scaled by
// -log2(e)), w = exp2(sigma_hat), blends 3 channels.
__global__ __launch_bounds__(256) void gv_kernel(
    const float* __restrict__ xyz,
    const float* __restrict__ chol,
    const float* __restrict__ feat,
    const float* __restrict__ opac,
    float* __restrict__ out)
{
    __shared__ __align__(16) float lds[NG * 8];

    const int tid = threadIdx.x;
    const int r0 = blockIdx.x * 2;          // first row index (r = t*128 + y)
    const float y0 = (float)(r0 & 127);
    const float t0 = (float)(r0 >> 7);
    const float y1 = (float)((r0 + 1) & 127);
    const float t1 = (float)((r0 + 1) >> 7);

    const float kneg = -1.44269504088896340736f;  // -log2(e)

    // ---- per-gaussian setup (4 gaussians per thread) ----
    for (int n = tid; n < NG; n += 256) {
        float vx = xyz[n * 3 + 0], vy = xyz[n * 3 + 1], vt = xyz[n * 3 + 2];
        float mx = 0.5f * ((tanhf(vx) + 1.f) * (float)WW - 1.f);
        float my = 0.5f * ((tanhf(vy) + 1.f) * (float)HH - 1.f);
        float mt = 0.5f * ((tanhf(vt) + 1.f) * (float)TT - 1.f);

        float c0 = chol[n * 6 + 0] + 0.5f;
        float c1 = chol[n * 6 + 1];
        float c2 = chol[n * 6 + 2] + 0.5f;
        float c3 = chol[n * 6 + 3] + 0.5f;
        float c4 = chol[n * 6 + 4];
        float c5 = chol[n * 6 + 5] + 0.5f;

        // Sigma = L L^T, L = [[c0,0,0],[c1,c3,0],[c2,c4,c5]]
        float a  = c0 * c0;
        float b  = c0 * c1;
        float cc = c0 * c2;
        float d  = c1 * c1 + c3 * c3;
        float e  = c1 * c2 + c3 * c4;
        float f  = c2 * c2 + c4 * c4 + c5 * c5;

        // symmetric 3x3 inverse via adjugate
        float A00 = d * f - e * e;
        float A01 = cc * e - b * f;
        float A02 = b * e - cc * d;
        float A11 = a * f - cc * cc;
        float A12 = b * cc - a * e;
        float A22 = a * d - b * b;
        float det = a * A00 + b * A01 + cc * A02;
        float rdet = 1.f / det;
        float Q00 = A00 * rdet, Q01 = A01 * rdet, Q02 = A02 * rdet;
        float Q11 = A11 * rdet, Q12 = A12 * rdet, Q22 = A22 * rdet;

        float qmx = Q00 * mx + Q01 * my + Q02 * mt;
        float qmy = Q01 * mx + Q11 * my + Q12 * mt;
        float qmt = Q02 * mx + Q12 * my + Q22 * mt;
        float cst = 0.5f * (mx * qmx + my * qmy + mt * qmt);

        // G coefficients (reference's [P,10]x[10,N] form)
        float G0 = 0.5f * Q00, G1 = 0.5f * Q11, G2 = 0.5f * Q22;
        float G3 = Q01, G4 = Q02, G5 = Q12;
        float G6 = -qmx, G7 = -qmy, G8 = -qmt, G9 = cst;

        // per-row quadratic-in-x coefficients, pre-scaled by -log2(e)
        float A_ = kneg * G0;
        float B0 = kneg * (G3 * y0 + G4 * t0 + G6);
        float C0 = kneg * (G1 * y0 * y0 + G2 * t0 * t0 + G5 * y0 * t0 + G7 * y0 + G8 * t0 + G9);
        float B1 = kneg * (G3 * y1 + G4 * t1 + G6);
        float C1 = kneg * (G1 * y1 * y1 + G2 * t1 * t1 + G5 * y1 * t1 + G7 * y1 + G8 * t1 + G9);

        float op = opac[n];
        lds[n * 8 + 0] = A_;
        lds[n * 8 + 1] = op * feat[n * 3 + 0];
        lds[n * 8 + 2] = op * feat[n * 3 + 1];
        lds[n * 8 + 3] = op * feat[n * 3 + 2];
        lds[n * 8 + 4] = B0;
        lds[n * 8 + 5] = C0;
        lds[n * 8 + 6] = B1;
        lds[n * 8 + 7] = C1;
    }
    __syncthreads();

    // ---- inner loop: 1024 gaussians per pixel ----
    const int ri = tid >> 7;                 // which of the block's 2 rows
    const float xf = (float)(tid & 127);
    float acc0 = 0.f, acc1 = 0.f, acc2 = 0.f;
    const float4* lds4 = (const float4*)lds;
    const float2* lds2 = (const float2*)lds;

#pragma unroll 8
    for (int n = 0; n < NG; ++n) {
        float4 af = lds4[n * 2];                 // {A, fc0, fc1, fc2} (broadcast)
        float2 bc = lds2[n * 4 + 2 + ri];        // {B, C} for my row (broadcast)
        float s = fmaf(fmaf(af.x, xf, bc.x), xf, bc.y);  // -log2e * sigma
        float w = __builtin_amdgcn_exp2f(s);
        acc0 = fmaf(w, af.y, acc0);
        acc1 = fmaf(w, af.z, acc1);
        acc2 = fmaf(w, af.w, acc2);
    }

    acc0 = fminf(fmaxf(acc0, 0.f), 1.f);
    acc1 = fminf(fmaxf(acc1, 0.f), 1.f);
    acc2 = fminf(fmaxf(acc2, 0.f), 1.f);

    // out[((c*H + y)*W + x)*T + t]
    const int r = r0 + ri;
    const int y = r & 127, t = r >> 7;
    const int x = tid & 127;
    const int base = (y * WW + x) * TT + t;
    out[base] = acc0;
    out[base + HH * WW * TT] = acc1;
    out[base + 2 * HH * WW * TT] = acc2;
}

extern "C" void kernel_launch(void* const* d_in, const int* in_sizes, int n_in,
                              void* d_out, int out_size, void* d_ws, size_t ws_size,
                              hipStream_t stream) {
    const float* xyz  = (const float*)d_in[0];
    const float* chol = (const float*)d_in[1];
    const float* feat = (const float*)d_in[2];
    const float* opac = (const float*)d_in[3];
    float* out = (float*)d_out;

    const int P = TT * HH * WW;              // 131072 pixels
    const int blocks = P / 256;              // 512 blocks, 2 rows each
    gv_kernel<<<blocks, 256, 0, stream>>>(xyz, chol, feat, opac, out);
}

// Round 2
// 43.004 us; speedup vs baseline: 1.0047x; 1.0047x over previous
//
#include <hip/hip_runtime.h>
#include <math.h>

#define HH 128
#define WW 128
#define TT 8
#define NG 1024
#define PP (HH * WW * TT)      // 131072 pixels
#define P3 (PP * 3)            // 393216 floats per full image

// ---------------------------------------------------------------------------
// Kernel 1: per-(pixel-block, gaussian-chunk) partial blend.
// Block = 256 threads = 2 rows (r = t*128 + y) of 128 x-values.
// blockIdx.y selects a CHUNK-sized slice of the gaussians.
// FINAL=true  -> single chunk, clip and write directly to out.
// FINAL=false -> write unclipped partial to dst + blockIdx.y * P3.
// ---------------------------------------------------------------------------
template <int CHUNK, bool FINAL>
__global__ __launch_bounds__(256) void gv_partial(
    const float* __restrict__ xyz,
    const float* __restrict__ chol,
    const float* __restrict__ feat,
    const float* __restrict__ opac,
    float* __restrict__ dst)
{
    __shared__ __align__(16) float lds[CHUNK * 8];

    const int tid = threadIdx.x;
    const int r0 = blockIdx.x * 2;          // first row index (r = t*128 + y)
    const int g0 = blockIdx.y * CHUNK;      // first gaussian of this chunk
    const float y0 = (float)(r0 & 127);
    const float t0 = (float)(r0 >> 7);
    const float y1 = (float)((r0 + 1) & 127);
    const float t1 = (float)((r0 + 1) >> 7);

    const float kneg = -1.44269504088896340736f;  // -log2(e)

    // ---- per-gaussian setup (CHUNK/256 gaussians per thread) ----
    for (int k = tid; k < CHUNK; k += 256) {
        const int n = g0 + k;
        float vx = xyz[n * 3 + 0], vy = xyz[n * 3 + 1], vt = xyz[n * 3 + 2];
        float mx = 0.5f * ((tanhf(vx) + 1.f) * (float)WW - 1.f);
        float my = 0.5f * ((tanhf(vy) + 1.f) * (float)HH - 1.f);
        float mt = 0.5f * ((tanhf(vt) + 1.f) * (float)TT - 1.f);

        float c0 = chol[n * 6 + 0] + 0.5f;
        float c1 = chol[n * 6 + 1];
        float c2 = chol[n * 6 + 2] + 0.5f;
        float c3 = chol[n * 6 + 3] + 0.5f;
        float c4 = chol[n * 6 + 4];
        float c5 = chol[n * 6 + 5] + 0.5f;

        // Sigma = L L^T, L = [[c0,0,0],[c1,c3,0],[c2,c4,c5]]
        float a  = c0 * c0;
        float b  = c0 * c1;
        float cc = c0 * c2;
        float d  = c1 * c1 + c3 * c3;
        float e  = c1 * c2 + c3 * c4;
        float f  = c2 * c2 + c4 * c4 + c5 * c5;

        // symmetric 3x3 inverse via adjugate
        float A00 = d * f - e * e;
        float A01 = cc * e - b * f;
        float A02 = b * e - cc * d;
        float A11 = a * f - cc * cc;
        float A12 = b * cc - a * e;
        float A22 = a * d - b * b;
        float det = a * A00 + b * A01 + cc * A02;
        float rdet = 1.f / det;
        float Q00 = A00 * rdet, Q01 = A01 * rdet, Q02 = A02 * rdet;
        float Q11 = A11 * rdet, Q12 = A12 * rdet, Q22 = A22 * rdet;

        float qmx = Q00 * mx + Q01 * my + Q02 * mt;
        float qmy = Q01 * mx + Q11 * my + Q12 * mt;
        float qmt = Q02 * mx + Q12 * my + Q22 * mt;
        float cst = 0.5f * (mx * qmx + my * qmy + mt * qmt);

        float G0 = 0.5f * Q00, G1 = 0.5f * Q11, G2 = 0.5f * Q22;
        float G3 = Q01, G4 = Q02, G5 = Q12;
        float G6 = -qmx, G7 = -qmy, G8 = -qmt, G9 = cst;

        // per-row quadratic-in-x coefficients, pre-scaled by -log2(e)
        float A_ = kneg * G0;
        float B0 = kneg * (G3 * y0 + G4 * t0 + G6);
        float C0 = kneg * (G1 * y0 * y0 + G2 * t0 * t0 + G5 * y0 * t0 + G7 * y0 + G8 * t0 + G9);
        float B1 = kneg * (G3 * y1 + G4 * t1 + G6);
        float C1 = kneg * (G1 * y1 * y1 + G2 * t1 * t1 + G5 * y1 * t1 + G7 * y1 + G8 * t1 + G9);

        float op = opac[n];
        lds[k * 8 + 0] = A_;
        lds[k * 8 + 1] = op * feat[n * 3 + 0];
        lds[k * 8 + 2] = op * feat[n * 3 + 1];
        lds[k * 8 + 3] = op * feat[n * 3 + 2];
        lds[k * 8 + 4] = B0;
        lds[k * 8 + 5] = C0;
        lds[k * 8 + 6] = B1;
        lds[k * 8 + 7] = C1;
    }
    __syncthreads();

    // ---- inner loop: CHUNK gaussians per pixel ----
    const int ri = tid >> 7;                 // which of the block's 2 rows
    const float xf = (float)(tid & 127);
    float acc0 = 0.f, acc1 = 0.f, acc2 = 0.f;
    const float4* lds4 = (const float4*)lds;
    const float2* lds2 = (const float2*)lds;

#pragma unroll 8
    for (int k = 0; k < CHUNK; ++k) {
        float4 af = lds4[k * 2];                 // {A, fc0, fc1, fc2} (broadcast)
        float2 bc = lds2[k * 4 + 2 + ri];        // {B, C} for my row (broadcast)
        float s = fmaf(fmaf(af.x, xf, bc.x), xf, bc.y);  // -log2e * sigma
        float w = __builtin_amdgcn_exp2f(s);
        acc0 = fmaf(w, af.y, acc0);
        acc1 = fmaf(w, af.z, acc1);
        acc2 = fmaf(w, af.w, acc2);
    }

    if (FINAL) {
        acc0 = fminf(fmaxf(acc0, 0.f), 1.f);
        acc1 = fminf(fmaxf(acc1, 0.f), 1.f);
        acc2 = fminf(fmaxf(acc2, 0.f), 1.f);
    }

    // layout: [3][H][W][T], base = (y*W + x)*T + t
    const int r = r0 + ri;
    const int y = r & 127, t = r >> 7;
    const int x = tid & 127;
    const int base = (y * WW + x) * TT + t;
    float* d = FINAL ? dst : (dst + (size_t)blockIdx.y * P3);
    d[base] = acc0;
    d[base + PP] = acc1;
    d[base + 2 * PP] = acc2;
}

// ---------------------------------------------------------------------------
// Kernel 2: sum SPLIT partials, clip, write out. Pure memory-bound.
// ---------------------------------------------------------------------------
__global__ __launch_bounds__(256) void gv_reduce(
    const float* __restrict__ ws, float* __restrict__ out, int split)
{
    const int i = blockIdx.x * 256 + threadIdx.x;   // float4 index, P3/4 total
    const float4* w4 = (const float4*)ws;
    float4 a = w4[i];
    for (int s = 1; s < split; ++s) {
        float4 b = w4[(size_t)s * (P3 / 4) + i];
        a.x += b.x; a.y += b.y; a.z += b.z; a.w += b.w;
    }
    a.x = fminf(fmaxf(a.x, 0.f), 1.f);
    a.y = fminf(fmaxf(a.y, 0.f), 1.f);
    a.z = fminf(fmaxf(a.z, 0.f), 1.f);
    a.w = fminf(fmaxf(a.w, 0.f), 1.f);
    ((float4*)out)[i] = a;
}

extern "C" void kernel_launch(void* const* d_in, const int* in_sizes, int n_in,
                              void* d_out, int out_size, void* d_ws, size_t ws_size,
                              hipStream_t stream) {
    const float* xyz  = (const float*)d_in[0];
    const float* chol = (const float*)d_in[1];
    const float* feat = (const float*)d_in[2];
    const float* opac = (const float*)d_in[3];
    float* out = (float*)d_out;
    float* ws  = (float*)d_ws;

    const int pixel_blocks = PP / 256;               // 512 (2 rows per block)
    const size_t bytes_per_split = (size_t)P3 * sizeof(float);

    if (ws_size >= 4 * bytes_per_split) {
        // SPLIT=4: 2048 blocks, 8 KB LDS each -> full occupancy headroom
        gv_partial<256, false><<<dim3(pixel_blocks, 4), 256, 0, stream>>>(
            xyz, chol, feat, opac, ws);
        gv_reduce<<<P3 / 4 / 256, 256, 0, stream>>>(ws, out, 4);
    } else if (ws_size >= 2 * bytes_per_split) {
        gv_partial<512, false><<<dim3(pixel_blocks, 2), 256, 0, stream>>>(
            xyz, chol, feat, opac, ws);
        gv_reduce<<<P3 / 4 / 256, 256, 0, stream>>>(ws, out, 2);
    } else {
        gv_partial<1024, true><<<dim3(pixel_blocks, 1), 256, 0, stream>>>(
            xyz, chol, feat, opac, out);
    }
}

// Round 3
// 38.151 us; speedup vs baseline: 1.1325x; 1.1272x over previous
//
#include <hip/hip_runtime.h>
#include <math.h>

#define HH 128
#define WW 128
#define TT 8
#define NG 1024
#define PP (HH * WW * TT)      // 131072 pixels
#define P3 (PP * 3)            // 393216 floats per full image

typedef float vf2 __attribute__((ext_vector_type(2)));

// ---------------------------------------------------------------------------
// Kernel 1: per-(pixel-block, gaussian-chunk) partial blend.
// Block = 256 threads = 4 rows (r = t*128 + y); each wave owns one row;
// each thread owns pixels x and x+64 of its row (packed fp32 pairs).
// blockIdx.y selects a CHUNK-sized slice of the gaussians.
// FINAL=true  -> single chunk, clip and write directly to out.
// FINAL=false -> write unclipped partial to dst + blockIdx.y * P3.
// LDS per gaussian: {A, f0*op, f1*op, f2*op, B0,C0, B1,C1, B2,C2, B3,C3}.
// ---------------------------------------------------------------------------
template <int CHUNK, bool FINAL>
__global__ __launch_bounds__(256) void gv_partial(
    const float* __restrict__ xyz,
    const float* __restrict__ chol,
    const float* __restrict__ feat,
    const float* __restrict__ opac,
    float* __restrict__ dst)
{
    __shared__ __align__(16) float lds[CHUNK * 12];

    const int tid = threadIdx.x;
    const int r0 = blockIdx.x * 4;          // first row index (r = t*128 + y)
    const int g0 = blockIdx.y * CHUNK;      // first gaussian of this chunk

    const float kneg = -1.44269504088896340736f;  // -log2(e)

    // ---- per-gaussian setup ----
    for (int k = tid; k < CHUNK; k += 256) {
        const int n = g0 + k;
        float vx = xyz[n * 3 + 0], vy = xyz[n * 3 + 1], vt = xyz[n * 3 + 2];
        float mx = 0.5f * ((tanhf(vx) + 1.f) * (float)WW - 1.f);
        float my = 0.5f * ((tanhf(vy) + 1.f) * (float)HH - 1.f);
        float mt = 0.5f * ((tanhf(vt) + 1.f) * (float)TT - 1.f);

        float c0 = chol[n * 6 + 0] + 0.5f;
        float c1 = chol[n * 6 + 1];
        float c2 = chol[n * 6 + 2] + 0.5f;
        float c3 = chol[n * 6 + 3] + 0.5f;
        float c4 = chol[n * 6 + 4];
        float c5 = chol[n * 6 + 5] + 0.5f;

        // Sigma = L L^T, L = [[c0,0,0],[c1,c3,0],[c2,c4,c5]]
        float a  = c0 * c0;
        float b  = c0 * c1;
        float cc = c0 * c2;
        float d  = c1 * c1 + c3 * c3;
        float e  = c1 * c2 + c3 * c4;
        float f  = c2 * c2 + c4 * c4 + c5 * c5;

        // symmetric 3x3 inverse via adjugate
        float A00 = d * f - e * e;
        float A01 = cc * e - b * f;
        float A02 = b * e - cc * d;
        float A11 = a * f - cc * cc;
        float A12 = b * cc - a * e;
        float A22 = a * d - b * b;
        float det = a * A00 + b * A01 + cc * A02;
        float rdet = 1.f / det;
        float Q00 = A00 * rdet, Q01 = A01 * rdet, Q02 = A02 * rdet;
        float Q11 = A11 * rdet, Q12 = A12 * rdet, Q22 = A22 * rdet;

        float qmx = Q00 * mx + Q01 * my + Q02 * mt;
        float qmy = Q01 * mx + Q11 * my + Q12 * mt;
        float qmt = Q02 * mx + Q12 * my + Q22 * mt;
        float cst = 0.5f * (mx * qmx + my * qmy + mt * qmt);

        float G0 = 0.5f * Q00, G1 = 0.5f * Q11, G2 = 0.5f * Q22;
        float G3 = Q01, G4 = Q02, G5 = Q12;
        float G6 = -qmx, G7 = -qmy, G8 = -qmt, G9 = cst;

        float A_ = kneg * G0;
        float op = opac[n];
        lds[k * 12 + 0] = A_;
        lds[k * 12 + 1] = op * feat[n * 3 + 0];
        lds[k * 12 + 2] = op * feat[n * 3 + 1];
        lds[k * 12 + 3] = op * feat[n * 3 + 2];
#pragma unroll
        for (int rr = 0; rr < 4; ++rr) {
            const int r = r0 + rr;
            const float yf = (float)(r & 127);
            const float tf = (float)(r >> 7);
            float B_ = kneg * (G3 * yf + G4 * tf + G6);
            float C_ = kneg * (G1 * yf * yf + G2 * tf * tf + G5 * yf * tf
                               + G7 * yf + G8 * tf + G9);
            lds[k * 12 + 4 + 2 * rr] = B_;
            lds[k * 12 + 5 + 2 * rr] = C_;
        }
    }
    __syncthreads();

    // ---- inner loop: CHUNK gaussians, 2 pixels per thread ----
    const int wv = tid >> 6;                 // wave index = row within block
    const float xf = (float)(tid & 63);
    const vf2 X = {xf, xf + 64.f};
    vf2 acc0 = {0.f, 0.f}, acc1 = {0.f, 0.f}, acc2 = {0.f, 0.f};
    const float4* lds4 = (const float4*)lds;
    const float2* lds2 = (const float2*)lds;

#pragma unroll 8
    for (int k = 0; k < CHUNK; ++k) {
        float4 af = lds4[k * 3];                 // {A, fc0, fc1, fc2} broadcast
        float2 bc = lds2[k * 6 + 2 + wv];        // {B, C} for my row, broadcast
        vf2 Av = {af.x, af.x};
        vf2 Bv = {bc.x, bc.x};
        vf2 Cv = {bc.y, bc.y};
        vf2 s = __builtin_elementwise_fma(
                    __builtin_elementwise_fma(Av, X, Bv), X, Cv);
        vf2 w;
        w.x = __builtin_amdgcn_exp2f(s.x);
        w.y = __builtin_amdgcn_exp2f(s.y);
        acc0 = __builtin_elementwise_fma(w, (vf2){af.y, af.y}, acc0);
        acc1 = __builtin_elementwise_fma(w, (vf2){af.z, af.z}, acc1);
        acc2 = __builtin_elementwise_fma(w, (vf2){af.w, af.w}, acc2);
    }

    if (FINAL) {
        acc0 = __builtin_elementwise_min(__builtin_elementwise_max(acc0, (vf2){0.f,0.f}), (vf2){1.f,1.f});
        acc1 = __builtin_elementwise_min(__builtin_elementwise_max(acc1, (vf2){0.f,0.f}), (vf2){1.f,1.f});
        acc2 = __builtin_elementwise_min(__builtin_elementwise_max(acc2, (vf2){0.f,0.f}), (vf2){1.f,1.f});
    }

    // layout: [3][H][W][T], base = (y*W + x)*T + t ; second pixel at x+64
    const int r = r0 + wv;
    const int y = r & 127, t = r >> 7;
    const int x = tid & 63;
    const int base = (y * WW + x) * TT + t;
    float* d = FINAL ? dst : (dst + (size_t)blockIdx.y * P3);
    d[base] = acc0.x;
    d[base + 64 * TT] = acc0.y;
    d[base + PP] = acc1.x;
    d[base + PP + 64 * TT] = acc1.y;
    d[base + 2 * PP] = acc2.x;
    d[base + 2 * PP + 64 * TT] = acc2.y;
}

// ---------------------------------------------------------------------------
// Kernel 2: sum SPLIT partials, clip, write out. Pure memory-bound.
// ---------------------------------------------------------------------------
__global__ __launch_bounds__(256) void gv_reduce(
    const float* __restrict__ ws, float* __restrict__ out, int split)
{
    const int i = blockIdx.x * 256 + threadIdx.x;   // float4 index, P3/4 total
    const float4* w4 = (const float4*)ws;
    float4 a = w4[i];
    for (int s = 1; s < split; ++s) {
        float4 b = w4[(size_t)s * (P3 / 4) + i];
        a.x += b.x; a.y += b.y; a.z += b.z; a.w += b.w;
    }
    a.x = fminf(fmaxf(a.x, 0.f), 1.f);
    a.y = fminf(fmaxf(a.y, 0.f), 1.f);
    a.z = fminf(fmaxf(a.z, 0.f), 1.f);
    a.w = fminf(fmaxf(a.w, 0.f), 1.f);
    ((float4*)out)[i] = a;
}

extern "C" void kernel_launch(void* const* d_in, const int* in_sizes, int n_in,
                              void* d_out, int out_size, void* d_ws, size_t ws_size,
                              hipStream_t stream) {
    const float* xyz  = (const float*)d_in[0];
    const float* chol = (const float*)d_in[1];
    const float* feat = (const float*)d_in[2];
    const float* opac = (const float*)d_in[3];
    float* out = (float*)d_out;
    float* ws  = (float*)d_ws;

    const int pixel_blocks = (PP / 128) / 4;         // 256 blocks, 4 rows each
    const size_t bytes_per_split = (size_t)P3 * sizeof(float);

    if (ws_size >= 8 * bytes_per_split) {
        gv_partial<128, false><<<dim3(pixel_blocks, 8), 256, 0, stream>>>(
            xyz, chol, feat, opac, ws);
        gv_reduce<<<P3 / 4 / 256, 256, 0, stream>>>(ws, out, 8);
    } else if (ws_size >= 4 * bytes_per_split) {
        gv_partial<256, false><<<dim3(pixel_blocks, 4), 256, 0, stream>>>(
            xyz, chol, feat, opac, ws);
        gv_reduce<<<P3 / 4 / 256, 256, 0, stream>>>(ws, out, 4);
    } else if (ws_size >= 2 * bytes_per_split) {
        gv_partial<512, false><<<dim3(pixel_blocks, 2), 256, 0, stream>>>(
            xyz, chol, feat, opac, ws);
        gv_reduce<<<P3 / 4 / 256, 256, 0, stream>>>(ws, out, 2);
    } else {
        gv_partial<1024, true><<<dim3(pixel_blocks, 1), 256, 0, stream>>>(
            xyz, chol, feat, opac, out);
    }
}